// Round 1
// baseline (3220.435 us; speedup 1.0000x reference)
//
#include <hip/hip_runtime.h>
#include <math.h>

#define B_ 4
#define S_ 2048
#define D_ 1024
#define E_ 16
#define DH_ 64
#define TOPK_ 8
#define MAXLEN_ 1228
#define CAPF 4.0f
#define EPS_ 1e-6f

// ---------------- Kernel 1: gating -> masked_t[e][b][s] ----------------
// One wave (64 lanes) per token. Top-8 selection is done on raw logits
// (softmax is monotonic), masked value stored is the softmax score.
__global__ __launch_bounds__(256) void gate_kernel(
    const float* __restrict__ X, const float* __restrict__ wg,
    const float* __restrict__ bg, float* __restrict__ masked_t) {
  int token = blockIdx.x * 4 + (threadIdx.x >> 6);  // b*S + s
  int lane = threadIdx.x & 63;
  int b = token / S_, s = token % S_;
  const float* xrow = X + (size_t)token * D_;
  float acc[E_];
#pragma unroll
  for (int e = 0; e < E_; e++) acc[e] = 0.f;
  for (int d = lane; d < D_; d += 64) {
    float xv = xrow[d];
    const float* wrow = wg + (size_t)d * E_;
#pragma unroll
    for (int e = 0; e < E_; e++) acc[e] += xv * wrow[e];
  }
#pragma unroll
  for (int e = 0; e < E_; e++) {
    float v = acc[e];
    for (int off = 32; off; off >>= 1) v += __shfl_xor(v, off);
    acc[e] = v;
  }
  if (lane == 0) {
    float lg[E_], sc[E_], mx = -1e30f;
#pragma unroll
    for (int e = 0; e < E_; e++) {
      lg[e] = acc[e] + bg[e];
      mx = fmaxf(mx, lg[e]);
    }
    float den = 0.f;
#pragma unroll
    for (int e = 0; e < E_; e++) {
      sc[e] = expf(lg[e] - mx);
      den += sc[e];
    }
#pragma unroll
    for (int e = 0; e < E_; e++) sc[e] /= den;
    // top-8 by logits (== top-8 by softmax), ties -> lower index
#pragma unroll
    for (int e = 0; e < E_; e++) {
      int rank = 0;
      for (int j = 0; j < E_; j++)
        if (lg[j] > lg[e] || (lg[j] == lg[e] && j < e)) rank++;
      float m = (rank < TOPK_) ? sc[e] : 0.f;
      masked_t[((size_t)e * B_ + b) * S_ + s] = m;
    }
  }
}

// ---------------- Kernel 2: route_t = masked/denom*CAP ----------------
__global__ __launch_bounds__(256) void route_kernel(
    const float* __restrict__ masked_t, float* __restrict__ route_t) {
  int i = blockIdx.x * blockDim.x + threadIdx.x;  // over E*S
  if (i >= E_ * S_) return;
  int e = i / S_, s = i % S_;
  float v[B_];
  float d = EPS_;
#pragma unroll
  for (int b = 0; b < B_; b++) {
    v[b] = masked_t[((size_t)e * B_ + b) * S_ + s];
    d += v[b];
  }
#pragma unroll
  for (int b = 0; b < B_; b++)
    route_t[((size_t)e * B_ + b) * S_ + s] = v[b] / d * CAPF;
}

// ---------------- Kernel 3: top-MAXLEN selection per (e,b) ----------------
// Exact lax.top_k semantics: sort (value_bits<<32 | (S-1-s)) descending,
// take first MAXLEN, emit their s ascending via flags + prefix scan.
__global__ __launch_bounds__(1024) void select_kernel(
    const float* __restrict__ route_t, int* __restrict__ seq_ids) {
  __shared__ unsigned long long keys[S_];
  __shared__ int flags[S_];
  __shared__ int sA[S_], sB[S_];
  int eb = blockIdx.x;
  const float* r = route_t + (size_t)eb * S_;
  int tid = threadIdx.x;
  for (int i = tid; i < S_; i += 1024) {
    unsigned int fb = __float_as_uint(r[i]);  // monotonic, r >= 0
    keys[i] = ((unsigned long long)fb << 32) | (unsigned int)(S_ - 1 - i);
  }
  __syncthreads();
  for (int k = 2; k <= S_; k <<= 1) {
    for (int j = k >> 1; j > 0; j >>= 1) {
      for (int i = tid; i < S_; i += 1024) {
        int ixj = i ^ j;
        if (ixj > i) {
          bool desc = ((i & k) == 0);
          unsigned long long a = keys[i], c = keys[ixj];
          bool sw = desc ? (a < c) : (a > c);
          if (sw) { keys[i] = c; keys[ixj] = a; }
        }
      }
      __syncthreads();
    }
  }
  for (int i = tid; i < S_; i += 1024) flags[i] = 0;
  __syncthreads();
  for (int i = tid; i < MAXLEN_; i += 1024) {
    int s = S_ - 1 - (int)(keys[i] & 0xFFFFFFFFull);
    flags[s] = 1;
  }
  __syncthreads();
  for (int i = tid; i < S_; i += 1024) sA[i] = flags[i];
  __syncthreads();
  int* src = sA;
  int* dst = sB;
  for (int off = 1; off < S_; off <<= 1) {
    for (int i = tid; i < S_; i += 1024)
      dst[i] = src[i] + ((i >= off) ? src[i - off] : 0);
    __syncthreads();
    int* t = src; src = dst; dst = t;
  }
  int* outp = seq_ids + (size_t)eb * MAXLEN_;
  for (int i = tid; i < S_; i += 1024)
    if (flags[i]) outp[src[i] - 1] = i;
}

// ---------------- Kernel 4: gathered QKV GEMM ----------------
// C[e,b] (MAXLEN x 192) = X[b, seq_ids[e,b], :] (MAXLEN x 1024) @ W_qkv[e]
__global__ __launch_bounds__(256) void qkv_kernel(
    const float* __restrict__ X, const float* __restrict__ Wqkv,
    const int* __restrict__ seq_ids, float* __restrict__ qkv) {
  const int BM = 64, BN = 64, BK = 16;
  __shared__ float As[BK][BM + 1];
  __shared__ float Bs[BK][BN + 1];
  __shared__ int rows[BM];
  int eb = blockIdx.z;
  int e = eb / B_, b = eb % B_;
  int mt = blockIdx.y, nt = blockIdx.x;
  int m0 = mt * BM, n0 = nt * BN;
  const int* sid = seq_ids + (size_t)eb * MAXLEN_;
  const float* Wm = Wqkv + (size_t)e * D_ * 192;
  int tid = threadIdx.x;
  if (tid < BM) {
    int m = m0 + tid;
    rows[tid] = (m < MAXLEN_) ? sid[m] : -1;
  }
  __syncthreads();
  float c[4][4] = {};
  int tm = (tid / 16) * 4, tn = (tid % 16) * 4;
  for (int k0 = 0; k0 < D_; k0 += BK) {
    for (int i = tid; i < BM * BK; i += 256) {
      int m = i / BK, k = i % BK;
      int row = rows[m];
      As[k][m] = (row >= 0) ? X[((size_t)b * S_ + row) * D_ + k0 + k] : 0.f;
    }
    for (int i = tid; i < BK * BN; i += 256) {
      int k = i / BN, n = i % BN;
      Bs[k][n] = Wm[(size_t)(k0 + k) * 192 + n0 + n];
    }
    __syncthreads();
#pragma unroll
    for (int kk = 0; kk < BK; kk++) {
      float a[4], bb[4];
#pragma unroll
      for (int x = 0; x < 4; x++) a[x] = As[kk][tm + x];
#pragma unroll
      for (int y = 0; y < 4; y++) bb[y] = Bs[kk][tn + y];
#pragma unroll
      for (int x = 0; x < 4; x++)
#pragma unroll
        for (int y = 0; y < 4; y++) c[x][y] += a[x] * bb[y];
    }
    __syncthreads();
  }
  float* outr = qkv + (size_t)eb * MAXLEN_ * 192;
#pragma unroll
  for (int x = 0; x < 4; x++) {
    int m = m0 + tm + x;
    if (m < MAXLEN_) {
#pragma unroll
      for (int y = 0; y < 4; y++) outr[(size_t)m * 192 + n0 + tn + y] = c[x][y];
    }
  }
}

// ---------------- Kernel 5: causal flash attention per (e,b) ----------------
// 64-row Q tiles; 4 threads per row; K/V tiles in LDS; online softmax.
__global__ __launch_bounds__(256) void attn_kernel(
    const float* __restrict__ qkv, float* __restrict__ ctx) {
  __shared__ float Ks[64][68];
  __shared__ float Vs[64][68];
  int qt = blockIdx.x, eb = blockIdx.y;
  const float* base = qkv + (size_t)eb * MAXLEN_ * 192;
  int tid = threadIdx.x;
  int q0 = qt * 64;
  int r = tid >> 2, q = tid & 3;
  int lane = tid & 63;
  int gq = q0 + r;
  // Q row into registers (4 threads per row read the same 256B; L2-cached)
  float qreg[64];
  {
    int m = (gq < MAXLEN_) ? gq : 0;
    const float* qp = base + (size_t)m * 192;
#pragma unroll
    for (int d = 0; d < 64; d += 4) {
      float4 v = *reinterpret_cast<const float4*>(qp + d);
      qreg[d] = v.x; qreg[d + 1] = v.y; qreg[d + 2] = v.z; qreg[d + 3] = v.w;
    }
  }
  float mrow = -1e30f, lrow = 0.f;
  float acc[16];
#pragma unroll
  for (int i = 0; i < 16; i++) acc[i] = 0.f;
  for (int kt = 0; kt <= qt; kt++) {
    int k0 = kt * 64;
    for (int i = tid; i < 64 * 64; i += 256) {
      int rr = i >> 6, d = i & 63;
      int m = k0 + rr;
      bool ok = (m < MAXLEN_);
      Ks[rr][d] = ok ? base[(size_t)m * 192 + 64 + d] : 0.f;
      Vs[rr][d] = ok ? base[(size_t)m * 192 + 128 + d] : 0.f;
    }
    __syncthreads();
    float p[16];
    float tmax = -1e30f;
#pragma unroll
    for (int jj = 0; jj < 16; jj++) {
      int j = q * 16 + jj;
      float s = 0.f;
#pragma unroll
      for (int d = 0; d < 64; d++) s += qreg[d] * Ks[j][d];
      s *= 0.125f;
      int gk = k0 + j;
      if (gk > gq || gk >= MAXLEN_) s = -1e9f;
      p[jj] = s;
      tmax = fmaxf(tmax, s);
    }
    tmax = fmaxf(tmax, __shfl_xor(tmax, 1));
    tmax = fmaxf(tmax, __shfl_xor(tmax, 2));
    float mnew = fmaxf(mrow, tmax);
    float corr = __expf(mrow - mnew);
    float psum = 0.f;
#pragma unroll
    for (int jj = 0; jj < 16; jj++) {
      p[jj] = __expf(p[jj] - mnew);
      psum += p[jj];
    }
    psum += __shfl_xor(psum, 1);
    psum += __shfl_xor(psum, 2);
    lrow = lrow * corr + psum;
    mrow = mnew;
#pragma unroll
    for (int i = 0; i < 16; i++) acc[i] *= corr;
#pragma unroll
    for (int qq = 0; qq < 4; qq++) {
#pragma unroll
      for (int jj = 0; jj < 16; jj++) {
        float pv = __shfl(p[jj], (lane & ~3) | qq, 64);
        int j = qq * 16 + jj;
#pragma unroll
        for (int i = 0; i < 16; i++) acc[i] += pv * Vs[j][q * 16 + i];
      }
    }
    __syncthreads();
  }
  if (gq < MAXLEN_) {
    float inv = 1.f / lrow;
    float* o = ctx + ((size_t)eb * MAXLEN_ + (size_t)gq) * DH_ + q * 16;
#pragma unroll
    for (int i = 0; i < 16; i++) o[i] = acc[i] * inv;
  }
}

// ---------------- Kernel 6: FF GEMM + scatter-add into y ----------------
// out[e,b] = ctx[e,b] (L x 64) @ W_ff[e] (64 x 1024) + b_ff[e]; y[b,sid[m],:] += out[m,:]
__global__ __launch_bounds__(256) void ff_kernel(
    const float* __restrict__ ctx, const float* __restrict__ Wff,
    const float* __restrict__ bff, const int* __restrict__ seq_ids,
    float* __restrict__ y) {
  const int BM = 64, BN = 64, K = 64;
  __shared__ float As[K][BM + 1];
  __shared__ float Bs[K][BN + 1];
  int eb = blockIdx.z;
  int e = eb / B_, b = eb % B_;
  int mt = blockIdx.y, nt = blockIdx.x;
  int m0 = mt * BM, n0 = nt * BN;
  const float* A = ctx + (size_t)eb * MAXLEN_ * DH_;
  const float* Wm = Wff + (size_t)e * DH_ * D_;
  int tid = threadIdx.x;
  for (int i = tid; i < BM * K; i += 256) {
    int m = i / K, k = i % K;
    int gm = m0 + m;
    As[k][m] = (gm < MAXLEN_) ? A[(size_t)gm * DH_ + k] : 0.f;
  }
  for (int i = tid; i < K * BN; i += 256) {
    int k = i / BN, n = i % BN;
    Bs[k][n] = Wm[(size_t)k * D_ + n0 + n];
  }
  __syncthreads();
  float c[4][4] = {};
  int tm = (tid / 16) * 4, tn = (tid % 16) * 4;
#pragma unroll
  for (int kk = 0; kk < K; kk++) {
    float a[4], bb[4];
#pragma unroll
    for (int x = 0; x < 4; x++) a[x] = As[kk][tm + x];
#pragma unroll
    for (int y0 = 0; y0 < 4; y0++) bb[y0] = Bs[kk][tn + y0];
#pragma unroll
    for (int x = 0; x < 4; x++)
#pragma unroll
      for (int y0 = 0; y0 < 4; y0++) c[x][y0] += a[x] * bb[y0];
  }
  const int* sid = seq_ids + (size_t)eb * MAXLEN_;
#pragma unroll
  for (int x = 0; x < 4; x++) {
    int gm = m0 + tm + x;
    if (gm < MAXLEN_) {
      int srow = sid[gm];
      float* yr = y + ((size_t)b * S_ + srow) * D_ + n0 + tn;
#pragma unroll
      for (int y0 = 0; y0 < 4; y0++)
        atomicAdd(&yr[y0], c[x][y0] + bff[(size_t)e * D_ + n0 + tn + y0]);
    }
  }
}

// ---------------- Kernel 7: LayerNorm ----------------
__global__ __launch_bounds__(256) void ln_kernel(
    const float* __restrict__ y, const float* __restrict__ gamma,
    const float* __restrict__ beta, float* __restrict__ out) {
  __shared__ float r1[256], r2[256];
  int row = blockIdx.x;
  const float* yr = y + (size_t)row * D_;
  int tid = threadIdx.x;
  float v[4];
  float s1 = 0.f, s2 = 0.f;
#pragma unroll
  for (int i = 0; i < 4; i++) {
    v[i] = yr[tid + 256 * i];
    s1 += v[i];
    s2 += v[i] * v[i];
  }
  r1[tid] = s1;
  r2[tid] = s2;
  __syncthreads();
  for (int off = 128; off; off >>= 1) {
    if (tid < off) {
      r1[tid] += r1[tid + off];
      r2[tid] += r2[tid + off];
    }
    __syncthreads();
  }
  float mu = r1[0] * (1.f / D_);
  float var = r2[0] * (1.f / D_) - mu * mu;
  float inv = rsqrtf(var + 1e-5f);
  float* orow = out + (size_t)row * D_;
#pragma unroll
  for (int i = 0; i < 4; i++) {
    int d = tid + 256 * i;
    orow[d] = (v[i] - mu) * inv * gamma[d] + beta[d];
  }
}

extern "C" void kernel_launch(void* const* d_in, const int* in_sizes, int n_in,
                              void* d_out, int out_size, void* d_ws, size_t ws_size,
                              hipStream_t stream) {
  const float* X = (const float*)d_in[0];
  // d_in[1] = attn_mask (causal, hardcoded)
  const float* w_gate = (const float*)d_in[2];
  const float* b_gate = (const float*)d_in[3];
  const float* W_qkv = (const float*)d_in[4];
  const float* W_ff = (const float*)d_in[5];
  const float* b_ff = (const float*)d_in[6];
  const float* ln_g = (const float*)d_in[7];
  const float* ln_b = (const float*)d_in[8];
  float* out = (float*)d_out;

  char* ws = (char*)d_ws;
  float* masked_t = (float*)(ws);                 // 524288 B
  float* route_t = (float*)(ws + 524288);         // 524288 B
  int* seq_ids = (int*)(ws + 1048576);            // 314368 B
  float* qkv = (float*)(ws + 1362944);            // 60358656 B
  float* ctx = (float*)(ws + 61721600);           // 20119552 B
  float* y = (float*)(ws + 81841152);             // 33554432 B -> 115395584 total

  hipMemcpyAsync(y, X, (size_t)B_ * S_ * D_ * sizeof(float),
                 hipMemcpyDeviceToDevice, stream);
  gate_kernel<<<2048, 256, 0, stream>>>(X, w_gate, b_gate, masked_t);
  route_kernel<<<(E_ * S_ + 255) / 256, 256, 0, stream>>>(masked_t, route_t);
  select_kernel<<<E_ * B_, 1024, 0, stream>>>(route_t, seq_ids);
  qkv_kernel<<<dim3(3, 20, E_ * B_), 256, 0, stream>>>(X, W_qkv, seq_ids, qkv);
  attn_kernel<<<dim3(20, E_ * B_), 256, 0, stream>>>(qkv, ctx);
  ff_kernel<<<dim3(16, 20, E_ * B_), 256, 0, stream>>>(ctx, W_ff, b_ff, seq_ids, y);
  ln_kernel<<<B_ * S_, 256, 0, stream>>>(y, ln_g, ln_b, out);
}

// Round 2
// 2818.846 us; speedup vs baseline: 1.1425x; 1.1425x over previous
//
#include <hip/hip_runtime.h>
#include <math.h>

#define B_ 4
#define S_ 2048
#define D_ 1024
#define E_ 16
#define DH_ 64
#define TOPK_ 8
#define MAXLEN_ 1228
#define CAPF 4.0f
#define EPS_ 1e-6f

__device__ inline float bf2f(unsigned short u) {
  return __uint_as_float(((unsigned)u) << 16);
}
__device__ inline unsigned short f2bf(float f) {
  unsigned u = __float_as_uint(f);
  unsigned r = (u + 0x7FFFu + ((u >> 16) & 1u)) >> 16;
  return (unsigned short)r;
}

// ---------------- Kernel 1: gating -> masked_t[e][b][s] ----------------
__global__ __launch_bounds__(256) void gate_kernel(
    const float* __restrict__ X, const float* __restrict__ wg,
    const float* __restrict__ bg, float* __restrict__ masked_t) {
  int token = blockIdx.x * 4 + (threadIdx.x >> 6);  // b*S + s
  int lane = threadIdx.x & 63;
  int b = token / S_, s = token % S_;
  const float* xrow = X + (size_t)token * D_;
  float acc[E_];
#pragma unroll
  for (int e = 0; e < E_; e++) acc[e] = 0.f;
  for (int d = lane; d < D_; d += 64) {
    float xv = xrow[d];
    const float* wrow = wg + (size_t)d * E_;
#pragma unroll
    for (int e = 0; e < E_; e++) acc[e] += xv * wrow[e];
  }
#pragma unroll
  for (int e = 0; e < E_; e++) {
    float v = acc[e];
    for (int off = 32; off; off >>= 1) v += __shfl_xor(v, off);
    acc[e] = v;
  }
  if (lane == 0) {
    float lg[E_], sc[E_], mx = -1e30f;
#pragma unroll
    for (int e = 0; e < E_; e++) {
      lg[e] = acc[e] + bg[e];
      mx = fmaxf(mx, lg[e]);
    }
    float den = 0.f;
#pragma unroll
    for (int e = 0; e < E_; e++) {
      sc[e] = expf(lg[e] - mx);
      den += sc[e];
    }
#pragma unroll
    for (int e = 0; e < E_; e++) sc[e] /= den;
#pragma unroll
    for (int e = 0; e < E_; e++) {
      int rank = 0;
      for (int j = 0; j < E_; j++)
        if (lg[j] > lg[e] || (lg[j] == lg[e] && j < e)) rank++;
      float m = (rank < TOPK_) ? sc[e] : 0.f;
      masked_t[((size_t)e * B_ + b) * S_ + s] = m;
    }
  }
}

// ---------------- Kernel 2: route_t = masked/denom*CAP ----------------
__global__ __launch_bounds__(256) void route_kernel(
    const float* __restrict__ masked_t, float* __restrict__ route_t) {
  int i = blockIdx.x * blockDim.x + threadIdx.x;  // over E*S
  if (i >= E_ * S_) return;
  int e = i / S_, s = i % S_;
  float v[B_];
  float d = EPS_;
#pragma unroll
  for (int b = 0; b < B_; b++) {
    v[b] = masked_t[((size_t)e * B_ + b) * S_ + s];
    d += v[b];
  }
#pragma unroll
  for (int b = 0; b < B_; b++)
    route_t[((size_t)e * B_ + b) * S_ + s] = v[b] / d * CAPF;
}

// ---------------- Kernel 3: top-MAXLEN selection per (e,b) ----------------
__global__ __launch_bounds__(1024) void select_kernel(
    const float* __restrict__ route_t, int* __restrict__ seq_ids) {
  __shared__ unsigned long long keys[S_];
  __shared__ int flags[S_];
  __shared__ int sA[S_], sB[S_];
  int eb = blockIdx.x;
  const float* r = route_t + (size_t)eb * S_;
  int tid = threadIdx.x;
  for (int i = tid; i < S_; i += 1024) {
    unsigned int fb = __float_as_uint(r[i]);  // monotonic, r >= 0
    keys[i] = ((unsigned long long)fb << 32) | (unsigned int)(S_ - 1 - i);
  }
  __syncthreads();
  for (int k = 2; k <= S_; k <<= 1) {
    for (int j = k >> 1; j > 0; j >>= 1) {
      for (int i = tid; i < S_; i += 1024) {
        int ixj = i ^ j;
        if (ixj > i) {
          bool desc = ((i & k) == 0);
          unsigned long long a = keys[i], c = keys[ixj];
          bool sw = desc ? (a < c) : (a > c);
          if (sw) { keys[i] = c; keys[ixj] = a; }
        }
      }
      __syncthreads();
    }
  }
  for (int i = tid; i < S_; i += 1024) flags[i] = 0;
  __syncthreads();
  for (int i = tid; i < MAXLEN_; i += 1024) {
    int s = S_ - 1 - (int)(keys[i] & 0xFFFFFFFFull);
    flags[s] = 1;
  }
  __syncthreads();
  for (int i = tid; i < S_; i += 1024) sA[i] = flags[i];
  __syncthreads();
  int* src = sA;
  int* dst = sB;
  for (int off = 1; off < S_; off <<= 1) {
    for (int i = tid; i < S_; i += 1024)
      dst[i] = src[i] + ((i >= off) ? src[i - off] : 0);
    __syncthreads();
    int* t = src; src = dst; dst = t;
  }
  int* outp = seq_ids + (size_t)eb * MAXLEN_;
  for (int i = tid; i < S_; i += 1024)
    if (flags[i]) outp[src[i] - 1] = i;
}

// ---------------- Kernel 4: gathered QKV GEMM ----------------
__global__ __launch_bounds__(256) void qkv_kernel(
    const float* __restrict__ X, const float* __restrict__ Wqkv,
    const int* __restrict__ seq_ids, float* __restrict__ qkv) {
  const int BM = 64, BN = 64, BK = 16;
  __shared__ float As[BK][BM + 1];
  __shared__ float Bs[BK][BN + 1];
  __shared__ int rows[BM];
  int eb = blockIdx.z;
  int e = eb / B_, b = eb % B_;
  int mt = blockIdx.y, nt = blockIdx.x;
  int m0 = mt * BM, n0 = nt * BN;
  const int* sid = seq_ids + (size_t)eb * MAXLEN_;
  const float* Wm = Wqkv + (size_t)e * D_ * 192;
  int tid = threadIdx.x;
  if (tid < BM) {
    int m = m0 + tid;
    rows[tid] = (m < MAXLEN_) ? sid[m] : -1;
  }
  __syncthreads();
  float c[4][4] = {};
  int tm = (tid / 16) * 4, tn = (tid % 16) * 4;
  for (int k0 = 0; k0 < D_; k0 += BK) {
    for (int i = tid; i < BM * BK; i += 256) {
      int m = i / BK, k = i % BK;
      int row = rows[m];
      As[k][m] = (row >= 0) ? X[((size_t)b * S_ + row) * D_ + k0 + k] : 0.f;
    }
    for (int i = tid; i < BK * BN; i += 256) {
      int k = i / BN, n = i % BN;
      Bs[k][n] = Wm[(size_t)(k0 + k) * 192 + n0 + n];
    }
    __syncthreads();
#pragma unroll
    for (int kk = 0; kk < BK; kk++) {
      float a[4], bb[4];
#pragma unroll
      for (int x = 0; x < 4; x++) a[x] = As[kk][tm + x];
#pragma unroll
      for (int y = 0; y < 4; y++) bb[y] = Bs[kk][tn + y];
#pragma unroll
      for (int x = 0; x < 4; x++)
#pragma unroll
        for (int y = 0; y < 4; y++) c[x][y] += a[x] * bb[y];
    }
    __syncthreads();
  }
  float* outr = qkv + (size_t)eb * MAXLEN_ * 192;
#pragma unroll
  for (int x = 0; x < 4; x++) {
    int m = m0 + tm + x;
    if (m < MAXLEN_) {
#pragma unroll
      for (int y = 0; y < 4; y++) outr[(size_t)m * 192 + n0 + tn + y] = c[x][y];
    }
  }
}

// ---------------- Kernel 5: causal flash attention per (e,b) ----------------
__global__ __launch_bounds__(256) void attn_kernel(
    const float* __restrict__ qkv, unsigned short* __restrict__ ctx) {
  __shared__ float Ks[64][68];
  __shared__ float Vs[64][68];
  int qt = blockIdx.x, eb = blockIdx.y;
  const float* base = qkv + (size_t)eb * MAXLEN_ * 192;
  int tid = threadIdx.x;
  int q0 = qt * 64;
  int r = tid >> 2, q = tid & 3;
  int lane = tid & 63;
  int gq = q0 + r;
  float qreg[64];
  {
    int m = (gq < MAXLEN_) ? gq : 0;
    const float* qp = base + (size_t)m * 192;
#pragma unroll
    for (int d = 0; d < 64; d += 4) {
      float4 v = *reinterpret_cast<const float4*>(qp + d);
      qreg[d] = v.x; qreg[d + 1] = v.y; qreg[d + 2] = v.z; qreg[d + 3] = v.w;
    }
  }
  float mrow = -1e30f, lrow = 0.f;
  float acc[16];
#pragma unroll
  for (int i = 0; i < 16; i++) acc[i] = 0.f;
  for (int kt = 0; kt <= qt; kt++) {
    int k0 = kt * 64;
    for (int i = tid; i < 64 * 64; i += 256) {
      int rr = i >> 6, d = i & 63;
      int m = k0 + rr;
      bool ok = (m < MAXLEN_);
      Ks[rr][d] = ok ? base[(size_t)m * 192 + 64 + d] : 0.f;
      Vs[rr][d] = ok ? base[(size_t)m * 192 + 128 + d] : 0.f;
    }
    __syncthreads();
    float p[16];
    float tmax = -1e30f;
#pragma unroll
    for (int jj = 0; jj < 16; jj++) {
      int j = q * 16 + jj;
      float s = 0.f;
#pragma unroll
      for (int d = 0; d < 64; d++) s += qreg[d] * Ks[j][d];
      s *= 0.125f;
      int gk = k0 + j;
      if (gk > gq || gk >= MAXLEN_) s = -1e9f;
      p[jj] = s;
      tmax = fmaxf(tmax, s);
    }
    tmax = fmaxf(tmax, __shfl_xor(tmax, 1));
    tmax = fmaxf(tmax, __shfl_xor(tmax, 2));
    float mnew = fmaxf(mrow, tmax);
    float corr = __expf(mrow - mnew);
    float psum = 0.f;
#pragma unroll
    for (int jj = 0; jj < 16; jj++) {
      p[jj] = __expf(p[jj] - mnew);
      psum += p[jj];
    }
    psum += __shfl_xor(psum, 1);
    psum += __shfl_xor(psum, 2);
    lrow = lrow * corr + psum;
    mrow = mnew;
#pragma unroll
    for (int i = 0; i < 16; i++) acc[i] *= corr;
#pragma unroll
    for (int qq = 0; qq < 4; qq++) {
#pragma unroll
      for (int jj = 0; jj < 16; jj++) {
        float pv = __shfl(p[jj], (lane & ~3) | qq, 64);
        int j = qq * 16 + jj;
#pragma unroll
        for (int i = 0; i < 16; i++) acc[i] += pv * Vs[j][q * 16 + i];
      }
    }
    __syncthreads();
  }
  if (gq < MAXLEN_) {
    float inv = 1.f / lrow;
    unsigned short* o = ctx + ((size_t)eb * MAXLEN_ + (size_t)gq) * DH_ + q * 16;
#pragma unroll
    for (int i = 0; i < 16; i++) o[i] = f2bf(acc[i] * inv);
  }
}

// ---------------- Kernel 6: FF GEMM -> out[e][m][:] (bf16, no atomics) ----
__global__ __launch_bounds__(256) void ff_out_kernel(
    const unsigned short* __restrict__ ctx, const float* __restrict__ Wff,
    const float* __restrict__ bff, unsigned short* __restrict__ outb, int b) {
  const int BM = 64, BN = 64, K = 64;
  __shared__ float As[K][BM + 1];
  __shared__ float Bs[K][BN + 1];
  int e = blockIdx.z;
  int mt = blockIdx.y, nt = blockIdx.x;
  int m0 = mt * BM, n0 = nt * BN;
  const unsigned short* A = ctx + (size_t)(e * B_ + b) * MAXLEN_ * DH_;
  const float* Wm = Wff + (size_t)e * DH_ * D_;
  int tid = threadIdx.x;
  for (int i = tid; i < BM * K; i += 256) {
    int m = i / K, k = i % K;
    int gm = m0 + m;
    As[k][m] = (gm < MAXLEN_) ? bf2f(A[(size_t)gm * DH_ + k]) : 0.f;
  }
  for (int i = tid; i < K * BN; i += 256) {
    int k = i / BN, n = i % BN;
    Bs[k][n] = Wm[(size_t)k * D_ + n0 + n];
  }
  __syncthreads();
  float c[4][4] = {};
  int tm = (tid / 16) * 4, tn = (tid % 16) * 4;
#pragma unroll
  for (int kk = 0; kk < K; kk++) {
    float a[4], bb[4];
#pragma unroll
    for (int x = 0; x < 4; x++) a[x] = As[kk][tm + x];
#pragma unroll
    for (int y0 = 0; y0 < 4; y0++) bb[y0] = Bs[kk][tn + y0];
#pragma unroll
    for (int x = 0; x < 4; x++)
#pragma unroll
      for (int y0 = 0; y0 < 4; y0++) c[x][y0] += a[x] * bb[y0];
  }
#pragma unroll
  for (int x = 0; x < 4; x++) {
    int gm = m0 + tm + x;
    if (gm < MAXLEN_) {
      ushort4 pk;
      pk.x = f2bf(c[x][0] + bff[(size_t)e * D_ + n0 + tn + 0]);
      pk.y = f2bf(c[x][1] + bff[(size_t)e * D_ + n0 + tn + 1]);
      pk.z = f2bf(c[x][2] + bff[(size_t)e * D_ + n0 + tn + 2]);
      pk.w = f2bf(c[x][3] + bff[(size_t)e * D_ + n0 + tn + 3]);
      *reinterpret_cast<ushort4*>(outb + ((size_t)e * MAXLEN_ + gm) * D_ + n0 + tn) = pk;
    }
  }
}

// ------- Kernel 7: per-token gather (binary search) + residual + LayerNorm -
__global__ __launch_bounds__(256) void gather_ln_kernel(
    const float* __restrict__ X, const unsigned short* __restrict__ outb,
    const int* __restrict__ seq_ids, const float* __restrict__ gamma,
    const float* __restrict__ beta, float* __restrict__ out, int b) {
  __shared__ int ms[E_];
  __shared__ float w1[4], w2[4];
  int s = blockIdx.x;
  int tid = threadIdx.x;
  if (tid < E_) {
    const int* sid = seq_ids + ((size_t)tid * B_ + b) * MAXLEN_;
    int lo = 0, hi = MAXLEN_;
    while (lo < hi) {
      int mid = (lo + hi) >> 1;
      if (sid[mid] < s) lo = mid + 1; else hi = mid;
    }
    ms[tid] = (lo < MAXLEN_ && sid[lo] == s) ? lo : -1;
  }
  __syncthreads();
  const float* xr = X + ((size_t)b * S_ + s) * D_;
  float4 xv = *reinterpret_cast<const float4*>(xr + tid * 4);
  float v[4] = {xv.x, xv.y, xv.z, xv.w};
#pragma unroll
  for (int e = 0; e < E_; e++) {
    int m = ms[e];
    if (m >= 0) {
      const unsigned short* orow = outb + ((size_t)e * MAXLEN_ + m) * D_;
      ushort4 u = *reinterpret_cast<const ushort4*>(orow + tid * 4);
      v[0] += bf2f(u.x); v[1] += bf2f(u.y); v[2] += bf2f(u.z); v[3] += bf2f(u.w);
    }
  }
  float s1 = v[0] + v[1] + v[2] + v[3];
  float s2 = v[0] * v[0] + v[1] * v[1] + v[2] * v[2] + v[3] * v[3];
  for (int off = 32; off; off >>= 1) {
    s1 += __shfl_xor(s1, off);
    s2 += __shfl_xor(s2, off);
  }
  int wv = tid >> 6;
  if ((tid & 63) == 0) { w1[wv] = s1; w2[wv] = s2; }
  __syncthreads();
  s1 = w1[0] + w1[1] + w1[2] + w1[3];
  s2 = w2[0] + w2[1] + w2[2] + w2[3];
  float mu = s1 * (1.f / D_);
  float var = s2 * (1.f / D_) - mu * mu;
  float inv = rsqrtf(var + 1e-5f);
  float4 g = *reinterpret_cast<const float4*>(gamma + tid * 4);
  float4 be = *reinterpret_cast<const float4*>(beta + tid * 4);
  float4 o;
  o.x = (v[0] - mu) * inv * g.x + be.x;
  o.y = (v[1] - mu) * inv * g.y + be.y;
  o.z = (v[2] - mu) * inv * g.z + be.z;
  o.w = (v[3] - mu) * inv * g.w + be.w;
  *reinterpret_cast<float4*>(out + ((size_t)b * S_ + s) * D_ + tid * 4) = o;
}

extern "C" void kernel_launch(void* const* d_in, const int* in_sizes, int n_in,
                              void* d_out, int out_size, void* d_ws, size_t ws_size,
                              hipStream_t stream) {
  const float* X = (const float*)d_in[0];
  // d_in[1] = attn_mask (causal, hardcoded)
  const float* w_gate = (const float*)d_in[2];
  const float* b_gate = (const float*)d_in[3];
  const float* W_qkv = (const float*)d_in[4];
  const float* W_ff = (const float*)d_in[5];
  const float* b_ff = (const float*)d_in[6];
  const float* ln_g = (const float*)d_in[7];
  const float* ln_b = (const float*)d_in[8];
  float* out = (float*)d_out;

  char* ws = (char*)d_ws;
  float* masked_t = (float*)(ws);                    //   524288 B
  float* route_t = (float*)(ws + 524288);            //   524288 B
  int* seq_ids = (int*)(ws + 1048576);               //   314368 B
  float* qkv = (float*)(ws + 1362944);               // 60358656 B (f32)
  unsigned short* ctx = (unsigned short*)(ws + 61721600);   // 10059776 B (bf16)
  unsigned short* outb = (unsigned short*)(ws + 71781376);  // 40239104 B (bf16, per-b)
  // total 112020480 B

  gate_kernel<<<2048, 256, 0, stream>>>(X, w_gate, b_gate, masked_t);
  route_kernel<<<(E_ * S_ + 255) / 256, 256, 0, stream>>>(masked_t, route_t);
  select_kernel<<<E_ * B_, 1024, 0, stream>>>(route_t, seq_ids);
  qkv_kernel<<<dim3(3, 20, E_ * B_), 256, 0, stream>>>(X, W_qkv, seq_ids, qkv);
  attn_kernel<<<dim3(20, E_ * B_), 256, 0, stream>>>(qkv, ctx);
  for (int b = 0; b < B_; b++) {
    ff_out_kernel<<<dim3(16, 20, E_), 256, 0, stream>>>(ctx, W_ff, b_ff, outb, b);
    gather_ln_kernel<<<S_, 256, 0, stream>>>(X, outb, seq_ids, ln_g, ln_b, out, b);
  }
}

// Round 3
// 777.872 us; speedup vs baseline: 4.1401x; 3.6238x over previous
//
#include <hip/hip_runtime.h>
#include <math.h>

#define B_ 4
#define S_ 2048
#define D_ 1024
#define E_ 16
#define DH_ 64
#define TOPK_ 8
#define MAXLEN_ 1228
#define CAPF 4.0f
#define EPS_ 1e-6f
#define NQT_ 20  // ceil(MAXLEN/64)

typedef __attribute__((ext_vector_type(8))) short bf16x8;
typedef __attribute__((ext_vector_type(4))) float f32x4;

__device__ inline f32x4 mfma16(bf16x8 a, bf16x8 b, f32x4 c) {
  return __builtin_amdgcn_mfma_f32_16x16x32_bf16(a, b, c, 0, 0, 0);
}
__device__ inline float bf2f(unsigned short u) {
  return __uint_as_float(((unsigned)u) << 16);
}
__device__ inline unsigned short f2bf(float f) {
  unsigned u = __float_as_uint(f);
  unsigned r = (u + 0x7FFFu + ((u >> 16) & 1u)) >> 16;
  return (unsigned short)r;
}
__device__ inline ushort4 pk4(float4 v) {
  ushort4 r;
  r.x = f2bf(v.x); r.y = f2bf(v.y); r.z = f2bf(v.z); r.w = f2bf(v.w);
  return r;
}
// XOR-swizzled LDS addressing (byte offsets). 128B rows / 64B rows.
__device__ inline int swz128(int row, int off) { return row * 128 + (off ^ ((row & 7) << 4)); }
__device__ inline int swz64(int row, int off) { return row * 64 + (off ^ ((row & 3) << 4)); }

// ---------------- Kernel 1: gating -> masked_t[e][b][s] ----------------
__global__ __launch_bounds__(256) void gate_kernel(
    const float* __restrict__ X, const float* __restrict__ wg,
    const float* __restrict__ bg, float* __restrict__ masked_t) {
  int token = blockIdx.x * 4 + (threadIdx.x >> 6);  // b*S + s
  int lane = threadIdx.x & 63;
  int b = token / S_, s = token % S_;
  const float* xrow = X + (size_t)token * D_;
  float acc[E_];
#pragma unroll
  for (int e = 0; e < E_; e++) acc[e] = 0.f;
  for (int d = lane; d < D_; d += 64) {
    float xv = xrow[d];
    const float* wrow = wg + (size_t)d * E_;
#pragma unroll
    for (int e = 0; e < E_; e++) acc[e] += xv * wrow[e];
  }
#pragma unroll
  for (int e = 0; e < E_; e++) {
    float v = acc[e];
    for (int off = 32; off; off >>= 1) v += __shfl_xor(v, off);
    acc[e] = v;
  }
  if (lane == 0) {
    float lg[E_], sc[E_], mx = -1e30f;
#pragma unroll
    for (int e = 0; e < E_; e++) {
      lg[e] = acc[e] + bg[e];
      mx = fmaxf(mx, lg[e]);
    }
    float den = 0.f;
#pragma unroll
    for (int e = 0; e < E_; e++) {
      sc[e] = expf(lg[e] - mx);
      den += sc[e];
    }
#pragma unroll
    for (int e = 0; e < E_; e++) sc[e] /= den;
#pragma unroll
    for (int e = 0; e < E_; e++) {
      int rank = 0;
      for (int j = 0; j < E_; j++)
        if (lg[j] > lg[e] || (lg[j] == lg[e] && j < e)) rank++;
      float m = (rank < TOPK_) ? sc[e] : 0.f;
      masked_t[((size_t)e * B_ + b) * S_ + s] = m;
    }
  }
}

// ---------------- Kernel 2: route_t = masked/denom*CAP ----------------
__global__ __launch_bounds__(256) void route_kernel(
    const float* __restrict__ masked_t, float* __restrict__ route_t) {
  int i = blockIdx.x * blockDim.x + threadIdx.x;  // over E*S
  if (i >= E_ * S_) return;
  int e = i / S_, s = i % S_;
  float v[B_];
  float d = EPS_;
#pragma unroll
  for (int b = 0; b < B_; b++) {
    v[b] = masked_t[((size_t)e * B_ + b) * S_ + s];
    d += v[b];
  }
#pragma unroll
  for (int b = 0; b < B_; b++)
    route_t[((size_t)e * B_ + b) * S_ + s] = v[b] / d * CAPF;
}

// ---------------- Kernel 3: top-MAXLEN selection per (e,b) ----------------
__global__ __launch_bounds__(1024) void select_kernel(
    const float* __restrict__ route_t, int* __restrict__ seq_ids) {
  __shared__ unsigned long long keys[S_];
  __shared__ int flags[S_];
  __shared__ int sA[S_], sB[S_];
  int eb = blockIdx.x;
  const float* r = route_t + (size_t)eb * S_;
  int tid = threadIdx.x;
  for (int i = tid; i < S_; i += 1024) {
    unsigned int fb = __float_as_uint(r[i]);  // monotonic, r >= 0
    keys[i] = ((unsigned long long)fb << 32) | (unsigned int)(S_ - 1 - i);
  }
  __syncthreads();
  for (int k = 2; k <= S_; k <<= 1) {
    for (int j = k >> 1; j > 0; j >>= 1) {
      for (int i = tid; i < S_; i += 1024) {
        int ixj = i ^ j;
        if (ixj > i) {
          bool desc = ((i & k) == 0);
          unsigned long long a = keys[i], c = keys[ixj];
          bool sw = desc ? (a < c) : (a > c);
          if (sw) { keys[i] = c; keys[ixj] = a; }
        }
      }
      __syncthreads();
    }
  }
  for (int i = tid; i < S_; i += 1024) flags[i] = 0;
  __syncthreads();
  for (int i = tid; i < MAXLEN_; i += 1024) {
    int s = S_ - 1 - (int)(keys[i] & 0xFFFFFFFFull);
    flags[s] = 1;
  }
  __syncthreads();
  for (int i = tid; i < S_; i += 1024) sA[i] = flags[i];
  __syncthreads();
  int* src = sA;
  int* dst = sB;
  for (int off = 1; off < S_; off <<= 1) {
    for (int i = tid; i < S_; i += 1024)
      dst[i] = src[i] + ((i >= off) ? src[i - off] : 0);
    __syncthreads();
    int* t = src; src = dst; dst = t;
  }
  int* outp = seq_ids + (size_t)eb * MAXLEN_;
  for (int i = tid; i < S_; i += 1024)
    if (flags[i]) outp[src[i] - 1] = i;
}

// ---------------- Kernel 4: gathered QKV GEMM (bf16 MFMA) ----------------
// qkv[eb][m][0:192] = X[b][sid[m]][:] @ Wqkv[e]  (output bf16)
__global__ __launch_bounds__(256) void qkv_kernel(
    const float* __restrict__ X, const float* __restrict__ Wqkv,
    const int* __restrict__ seq_ids, unsigned short* __restrict__ qkv) {
  __shared__ __align__(16) char As_[64 * 64];    // [64 m][32 k] bf16, swz64
  __shared__ __align__(16) char Bt_[192 * 64];   // [192 n][32 k] bf16, swz64
  __shared__ int rows[64];
  int eb = blockIdx.y;
  int e = eb >> 2, b = eb & 3;
  int m0 = blockIdx.x * 64;
  int tid = threadIdx.x;
  int w = tid >> 6, l = tid & 63, lr = l & 15, lg = l >> 4;
  const int* sid = seq_ids + (size_t)eb * MAXLEN_;
  if (tid < 64) {
    int m = m0 + tid;
    rows[tid] = (m < MAXLEN_) ? sid[m] : 0;
  }
  __syncthreads();
  const float* Wm = Wqkv + (size_t)e * D_ * 192;
  const float* Xb = X + (size_t)b * S_ * D_;
  f32x4 acc[12];
#pragma unroll
  for (int nb = 0; nb < 12; nb++) acc[nb] = (f32x4){0.f, 0.f, 0.f, 0.f};
  for (int k0 = 0; k0 < D_; k0 += 32) {
    // stage A (gathered X rows), 64x32 f32 -> bf16
#pragma unroll
    for (int it = 0; it < 2; it++) {
      int idx = tid + it * 256;  // 0..511
      int row = idx >> 3, kq = (idx & 7) * 4;
      float4 xv = *reinterpret_cast<const float4*>(Xb + (size_t)rows[row] * D_ + k0 + kq);
      *reinterpret_cast<ushort4*>(As_ + swz64(row, kq * 2)) = pk4(xv);
    }
    // stage B^T: Bt[n][k] from W[k][n]
#pragma unroll
    for (int it = 0; it < 6; it++) {
      int idx = tid + it * 256;  // 0..1535
      int k = idx / 48, nq = (idx % 48) * 4;
      float4 wv = *reinterpret_cast<const float4*>(Wm + (size_t)(k0 + k) * 192 + nq);
      *reinterpret_cast<unsigned short*>(Bt_ + swz64(nq + 0, k * 2)) = f2bf(wv.x);
      *reinterpret_cast<unsigned short*>(Bt_ + swz64(nq + 1, k * 2)) = f2bf(wv.y);
      *reinterpret_cast<unsigned short*>(Bt_ + swz64(nq + 2, k * 2)) = f2bf(wv.z);
      *reinterpret_cast<unsigned short*>(Bt_ + swz64(nq + 3, k * 2)) = f2bf(wv.w);
    }
    __syncthreads();
    bf16x8 af = *reinterpret_cast<bf16x8*>(As_ + swz64(w * 16 + lr, lg * 16));
#pragma unroll
    for (int nb = 0; nb < 12; nb++) {
      bf16x8 bfr = *reinterpret_cast<bf16x8*>(Bt_ + swz64(nb * 16 + lr, lg * 16));
      acc[nb] = mfma16(af, bfr, acc[nb]);
    }
    __syncthreads();
  }
  unsigned short* outp = qkv + (size_t)eb * MAXLEN_ * 192;
#pragma unroll
  for (int nb = 0; nb < 12; nb++) {
#pragma unroll
    for (int i = 0; i < 4; i++) {
      int m = m0 + w * 16 + lg * 4 + i;
      if (m < MAXLEN_) outp[(size_t)m * 192 + nb * 16 + lr] = f2bf(acc[nb][i]);
    }
  }
}

// ------------- Kernel 5: flash attention, bf16 MFMA, per (e,b) -------------
// Per 64-row Q tile: compute S^T = K.Q^T (wave owns 16 q columns), online
// softmax per q (column = lane), P via swizzled LDS, O^T = V^T.P^T.
__global__ __launch_bounds__(256) void attn_kernel(
    const unsigned short* __restrict__ qkv, unsigned short* __restrict__ ctx) {
  __shared__ __align__(16) char Ks_[64 * 128];   // [64 k][64 d] bf16 swz128
  __shared__ __align__(16) char Vt_[64 * 128];   // [64 dv][64 k] bf16 swz128
  __shared__ __align__(16) char Pl_[4 * 16 * 128];  // per-wave [16 q][64 k]
  int qt = (NQT_ - 1) - blockIdx.x;  // longest blocks first
  int eb = blockIdx.y;
  const unsigned short* base = qkv + (size_t)eb * MAXLEN_ * 192;
  int tid = threadIdx.x;
  int w = tid >> 6, l = tid & 63, lr = l & 15, lg = l >> 4;
  int q0 = qt * 64;
  int gq = q0 + w * 16 + lr;  // this lane's q column
  // Q fragments (2 d-steps of 32), scale 1/8 folded in
  bf16x8 qf[2];
  {
    int m = (gq < MAXLEN_) ? gq : 0;
    const unsigned short* qp = base + (size_t)m * 192;
#pragma unroll
    for (int ds = 0; ds < 2; ds++) {
      int d0 = ds * 32 + lg * 8;
#pragma unroll
      for (int j = 0; j < 8; j++)
        qf[ds][j] = (short)f2bf(bf2f(qp[d0 + j]) * 0.125f);
    }
  }
  f32x4 acc[4];
#pragma unroll
  for (int db = 0; db < 4; db++) acc[db] = (f32x4){0.f, 0.f, 0.f, 0.f};
  float mrow = -1e30f, lsum = 0.f;
  char* Pw = Pl_ + w * 2048;
  for (int kt = 0; kt <= qt; kt++) {
    int k0 = kt * 64;
    // stage K rows and V transposed (zero-fill OOB rows: NaN hazard)
#pragma unroll
    for (int it = 0; it < 4; it++) {
      int idx = tid + it * 256;  // 0..1023
      int row = idx >> 4, cq = (idx & 15) * 4;
      int m = k0 + row;
      ushort4 kv, vv;
      if (m < MAXLEN_) {
        kv = *reinterpret_cast<const ushort4*>(base + (size_t)m * 192 + 64 + cq);
        vv = *reinterpret_cast<const ushort4*>(base + (size_t)m * 192 + 128 + cq);
      } else {
        kv.x = kv.y = kv.z = kv.w = 0;
        vv.x = vv.y = vv.z = vv.w = 0;
      }
      *reinterpret_cast<ushort4*>(Ks_ + swz128(row, cq * 2)) = kv;
      *reinterpret_cast<unsigned short*>(Vt_ + swz128(cq + 0, row * 2)) = vv.x;
      *reinterpret_cast<unsigned short*>(Vt_ + swz128(cq + 1, row * 2)) = vv.y;
      *reinterpret_cast<unsigned short*>(Vt_ + swz128(cq + 2, row * 2)) = vv.z;
      *reinterpret_cast<unsigned short*>(Vt_ + swz128(cq + 3, row * 2)) = vv.w;
    }
    __syncthreads();
    // S^T = K . Q^T : 4 k-blocks x 2 d-steps
    f32x4 sac[4];
#pragma unroll
    for (int kb = 0; kb < 4; kb++) {
      sac[kb] = (f32x4){0.f, 0.f, 0.f, 0.f};
#pragma unroll
      for (int ds = 0; ds < 2; ds++) {
        bf16x8 kf = *reinterpret_cast<bf16x8*>(Ks_ + swz128(kb * 16 + lr, ds * 64 + lg * 16));
        sac[kb] = mfma16(kf, qf[ds], sac[kb]);
      }
    }
    // mask + online softmax (per-lane = per-q-column)
    float p[16];
    float tmax = -1e30f;
#pragma unroll
    for (int kb = 0; kb < 4; kb++) {
#pragma unroll
      for (int i = 0; i < 4; i++) {
        int k = k0 + kb * 16 + lg * 4 + i;
        float s = sac[kb][i];
        if (k > gq || k >= MAXLEN_) s = -1e9f;
        p[kb * 4 + i] = s;
        tmax = fmaxf(tmax, s);
      }
    }
    tmax = fmaxf(tmax, __shfl_xor(tmax, 16));
    tmax = fmaxf(tmax, __shfl_xor(tmax, 32));
    float mnew = fmaxf(mrow, tmax);
    float corr = __expf(mrow - mnew);
    float psum = 0.f;
#pragma unroll
    for (int j = 0; j < 16; j++) {
      p[j] = __expf(p[j] - mnew);
      psum += p[j];
    }
    psum += __shfl_xor(psum, 16);
    psum += __shfl_xor(psum, 32);
    lsum = lsum * corr + psum;
    mrow = mnew;
#pragma unroll
    for (int db = 0; db < 4; db++) acc[db] = acc[db] * corr;
    // P^T -> bf16 -> per-wave LDS [q][k]
#pragma unroll
    for (int kb = 0; kb < 4; kb++) {
#pragma unroll
      for (int ip = 0; ip < 2; ip++) {
        unsigned u = (unsigned)f2bf(p[kb * 4 + ip * 2]) |
                     ((unsigned)f2bf(p[kb * 4 + ip * 2 + 1]) << 16);
        int k = kb * 16 + lg * 4 + ip * 2;
        *reinterpret_cast<unsigned*>(Pw + swz128(lr, k * 2)) = u;
      }
    }
    // O^T += V^T . P^T
    bf16x8 pf[2];
#pragma unroll
    for (int ks = 0; ks < 2; ks++)
      pf[ks] = *reinterpret_cast<bf16x8*>(Pw + swz128(lr, ks * 64 + lg * 16));
#pragma unroll
    for (int db = 0; db < 4; db++) {
#pragma unroll
      for (int ks = 0; ks < 2; ks++) {
        bf16x8 vf = *reinterpret_cast<bf16x8*>(Vt_ + swz128(db * 16 + lr, ks * 64 + lg * 16));
        acc[db] = mfma16(vf, pf[ks], acc[db]);
      }
    }
    __syncthreads();
  }
  if (gq < MAXLEN_) {
    float inv = 1.f / lsum;
    unsigned short* op = ctx + ((size_t)eb * MAXLEN_ + gq) * DH_;
#pragma unroll
    for (int db = 0; db < 4; db++) {
#pragma unroll
      for (int ip = 0; ip < 2; ip++) {
        unsigned u = (unsigned)f2bf(acc[db][ip * 2] * inv) |
                     ((unsigned)f2bf(acc[db][ip * 2 + 1] * inv) << 16);
        *reinterpret_cast<unsigned*>(op + db * 16 + lg * 4 + ip * 2) = u;
      }
    }
  }
}

// ------- Kernel 6: FF GEMM (bf16 MFMA) -> outb[e][m][:] for batch b -------
__global__ __launch_bounds__(256) void ff_kernel(
    const unsigned short* __restrict__ ctx, const float* __restrict__ Wff,
    const float* __restrict__ bff, unsigned short* __restrict__ outb, int b) {
  __shared__ __align__(16) char As_[128 * 128];  // [128 m][64 k] bf16 swz128
  __shared__ __align__(16) char Bt_[128 * 128];  // [128 n][64 k] bf16 swz128
  int e = blockIdx.z;
  int m0 = blockIdx.y * 128, n0 = blockIdx.x * 128;
  int tid = threadIdx.x;
  int w = tid >> 6, l = tid & 63, lr = l & 15, lg = l >> 4;
  const unsigned short* A = ctx + (size_t)(e * B_ + b) * MAXLEN_ * DH_;
  const float* Wm = Wff + (size_t)e * DH_ * D_;
  // stage A (bf16 passthrough)
#pragma unroll
  for (int it = 0; it < 8; it++) {
    int idx = tid + it * 256;  // 0..2047
    int row = idx >> 4, kq = (idx & 15) * 4;
    int gm = m0 + row;
    if (gm >= MAXLEN_) gm = MAXLEN_ - 1;
    ushort4 av = *reinterpret_cast<const ushort4*>(A + (size_t)gm * DH_ + kq);
    *reinterpret_cast<ushort4*>(As_ + swz128(row, kq * 2)) = av;
  }
  // stage B^T from W_ff f32 [64][1024]
#pragma unroll
  for (int it = 0; it < 8; it++) {
    int idx = tid + it * 256;  // 0..2047
    int k = idx >> 5, nq = (idx & 31) * 4;
    float4 wv = *reinterpret_cast<const float4*>(Wm + (size_t)k * D_ + n0 + nq);
    *reinterpret_cast<unsigned short*>(Bt_ + swz128(nq + 0, k * 2)) = f2bf(wv.x);
    *reinterpret_cast<unsigned short*>(Bt_ + swz128(nq + 1, k * 2)) = f2bf(wv.y);
    *reinterpret_cast<unsigned short*>(Bt_ + swz128(nq + 2, k * 2)) = f2bf(wv.z);
    *reinterpret_cast<unsigned short*>(Bt_ + swz128(nq + 3, k * 2)) = f2bf(wv.w);
  }
  __syncthreads();
  int wm = w >> 1, wn = w & 1;
  f32x4 acc[4][4];
#pragma unroll
  for (int mb = 0; mb < 4; mb++)
#pragma unroll
    for (int nb = 0; nb < 4; nb++) acc[mb][nb] = (f32x4){0.f, 0.f, 0.f, 0.f};
#pragma unroll
  for (int ks = 0; ks < 2; ks++) {
    bf16x8 af[4], bfr[4];
#pragma unroll
    for (int mb = 0; mb < 4; mb++)
      af[mb] = *reinterpret_cast<bf16x8*>(As_ + swz128(wm * 64 + mb * 16 + lr, ks * 64 + lg * 16));
#pragma unroll
    for (int nb = 0; nb < 4; nb++)
      bfr[nb] = *reinterpret_cast<bf16x8*>(Bt_ + swz128(wn * 64 + nb * 16 + lr, ks * 64 + lg * 16));
#pragma unroll
    for (int mb = 0; mb < 4; mb++)
#pragma unroll
      for (int nb = 0; nb < 4; nb++)
        acc[mb][nb] = mfma16(af[mb], bfr[nb], acc[mb][nb]);
  }
  float bias[4];
#pragma unroll
  for (int nb = 0; nb < 4; nb++)
    bias[nb] = bff[(size_t)e * D_ + n0 + wn * 64 + nb * 16 + lr];
#pragma unroll
  for (int mb = 0; mb < 4; mb++) {
#pragma unroll
    for (int i = 0; i < 4; i++) {
      int m = m0 + wm * 64 + mb * 16 + lg * 4 + i;
      if (m < MAXLEN_) {
        unsigned short* orow = outb + ((size_t)e * MAXLEN_ + m) * D_ + n0 + wn * 64;
#pragma unroll
        for (int nb = 0; nb < 4; nb++)
          orow[nb * 16 + lr] = f2bf(acc[mb][nb][i] + bias[nb]);
      }
    }
  }
}

// ------- Kernel 7: per-token gather (binary search) + residual + LayerNorm -
__global__ __launch_bounds__(256) void gather_ln_kernel(
    const float* __restrict__ X, const unsigned short* __restrict__ outb,
    const int* __restrict__ seq_ids, const float* __restrict__ gamma,
    const float* __restrict__ beta, float* __restrict__ out, int b) {
  __shared__ int ms[E_];
  __shared__ float w1[4], w2[4];
  int s = blockIdx.x;
  int tid = threadIdx.x;
  if (tid < E_) {
    const int* sid = seq_ids + ((size_t)tid * B_ + b) * MAXLEN_;
    int lo = 0, hi = MAXLEN_;
    while (lo < hi) {
      int mid = (lo + hi) >> 1;
      if (sid[mid] < s) lo = mid + 1; else hi = mid;
    }
    ms[tid] = (lo < MAXLEN_ && sid[lo] == s) ? lo : -1;
  }
  __syncthreads();
  const float* xr = X + ((size_t)b * S_ + s) * D_;
  float4 xv = *reinterpret_cast<const float4*>(xr + tid * 4);
  float v[4] = {xv.x, xv.y, xv.z, xv.w};
#pragma unroll
  for (int e = 0; e < E_; e++) {
    int m = ms[e];
    if (m >= 0) {
      const unsigned short* orow = outb + ((size_t)e * MAXLEN_ + m) * D_;
      ushort4 u = *reinterpret_cast<const ushort4*>(orow + tid * 4);
      v[0] += bf2f(u.x); v[1] += bf2f(u.y); v[2] += bf2f(u.z); v[3] += bf2f(u.w);
    }
  }
  float s1 = v[0] + v[1] + v[2] + v[3];
  float s2 = v[0] * v[0] + v[1] * v[1] + v[2] * v[2] + v[3] * v[3];
  for (int off = 32; off; off >>= 1) {
    s1 += __shfl_xor(s1, off);
    s2 += __shfl_xor(s2, off);
  }
  int wv = tid >> 6;
  if ((tid & 63) == 0) { w1[wv] = s1; w2[wv] = s2; }
  __syncthreads();
  s1 = w1[0] + w1[1] + w1[2] + w1[3];
  s2 = w2[0] + w2[1] + w2[2] + w2[3];
  float mu = s1 * (1.f / D_);
  float var = s2 * (1.f / D_) - mu * mu;
  float inv = rsqrtf(var + 1e-5f);
  float4 g = *reinterpret_cast<const float4*>(gamma + tid * 4);
  float4 be = *reinterpret_cast<const float4*>(beta + tid * 4);
  float4 o;
  o.x = (v[0] - mu) * inv * g.x + be.x;
  o.y = (v[1] - mu) * inv * g.y + be.y;
  o.z = (v[2] - mu) * inv * g.z + be.z;
  o.w = (v[3] - mu) * inv * g.w + be.w;
  *reinterpret_cast<float4*>(out + ((size_t)b * S_ + s) * D_ + tid * 4) = o;
}

extern "C" void kernel_launch(void* const* d_in, const int* in_sizes, int n_in,
                              void* d_out, int out_size, void* d_ws, size_t ws_size,
                              hipStream_t stream) {
  const float* X = (const float*)d_in[0];
  // d_in[1] = attn_mask (causal, hardcoded)
  const float* w_gate = (const float*)d_in[2];
  const float* b_gate = (const float*)d_in[3];
  const float* W_qkv = (const float*)d_in[4];
  const float* W_ff = (const float*)d_in[5];
  const float* b_ff = (const float*)d_in[6];
  const float* ln_g = (const float*)d_in[7];
  const float* ln_b = (const float*)d_in[8];
  float* out = (float*)d_out;

  char* ws = (char*)d_ws;
  float* masked_t = (float*)(ws);                           //   524288 B
  float* route_t = (float*)(ws + 524288);                   //   524288 B
  int* seq_ids = (int*)(ws + 1048576);                      //   314368 B
  unsigned short* qkv = (unsigned short*)(ws + 1362944);    // 30179328 B (bf16)
  unsigned short* ctx = (unsigned short*)(ws + 31542272);   // 10059776 B (bf16)
  unsigned short* outb = (unsigned short*)(ws + 41602048);  // 40239104 B (bf16)
  // total 81841152 B

  gate_kernel<<<2048, 256, 0, stream>>>(X, w_gate, b_gate, masked_t);
  route_kernel<<<(E_ * S_ + 255) / 256, 256, 0, stream>>>(masked_t, route_t);
  select_kernel<<<E_ * B_, 1024, 0, stream>>>(route_t, seq_ids);
  qkv_kernel<<<dim3(20, 64), 256, 0, stream>>>(X, W_qkv, seq_ids, qkv);
  attn_kernel<<<dim3(NQT_, 64), 256, 0, stream>>>(qkv, ctx);
  for (int b = 0; b < B_; b++) {
    ff_kernel<<<dim3(8, 10, 16), 256, 0, stream>>>(ctx, W_ff, b_ff, outb, b);
    gather_ln_kernel<<<S_, 256, 0, stream>>>(X, outb, seq_ids, ln_g, ln_b, out, b);
  }
}

// Round 4
// 375.743 us; speedup vs baseline: 8.5708x; 2.0702x over previous
//
#include <hip/hip_runtime.h>
#include <math.h>

#define B_ 4
#define S_ 2048
#define D_ 1024
#define E_ 16
#define DH_ 64
#define TOPK_ 8
#define MAXLEN_ 1228
#define CAPF 4.0f
#define EPS_ 1e-6f
#define NQT_ 20  // ceil(MAXLEN/64)

typedef __attribute__((ext_vector_type(8))) short bf16x8;
typedef __attribute__((ext_vector_type(4))) float f32x4;

__device__ inline f32x4 mfma16(bf16x8 a, bf16x8 b, f32x4 c) {
  return __builtin_amdgcn_mfma_f32_16x16x32_bf16(a, b, c, 0, 0, 0);
}
__device__ inline float bf2f(unsigned short u) {
  return __uint_as_float(((unsigned)u) << 16);
}
__device__ inline unsigned short f2bf(float f) {
  unsigned u = __float_as_uint(f);
  unsigned r = (u + 0x7FFFu + ((u >> 16) & 1u)) >> 16;
  return (unsigned short)r;
}
__device__ inline ushort4 pk4(float4 v) {
  ushort4 r;
  r.x = f2bf(v.x); r.y = f2bf(v.y); r.z = f2bf(v.z); r.w = f2bf(v.w);
  return r;
}
// XOR-swizzled LDS addressing (byte offsets). 128B rows / 64B rows.
__device__ inline int swz128(int row, int off) { return row * 128 + (off ^ ((row & 7) << 4)); }
__device__ inline int swz64(int row, int off) { return row * 64 + (off ^ ((row & 3) << 4)); }

// ---------------- one-time converts ----------------
__global__ __launch_bounds__(256) void cvt_x_kernel(
    const float* __restrict__ X, unsigned short* __restrict__ Xb) {
  size_t i = ((size_t)blockIdx.x * 256 + threadIdx.x) * 8;
  float4 a = *reinterpret_cast<const float4*>(X + i);
  float4 b = *reinterpret_cast<const float4*>(X + i + 4);
  *reinterpret_cast<ushort4*>(Xb + i) = pk4(a);
  *reinterpret_cast<ushort4*>(Xb + i + 4) = pk4(b);
}

// W_qkv[e][1024 k][192 n] f32 -> Wt[e][192 n][1024 k] bf16
__global__ __launch_bounds__(256) void cvt_wqkv_kernel(
    const float* __restrict__ W, unsigned short* __restrict__ Wt) {
  __shared__ short T[192][40];
  int e = blockIdx.y, k0 = blockIdx.x * 32;
  const float* Wp = W + (size_t)e * D_ * 192 + (size_t)k0 * 192;
  int tid = threadIdx.x;
#pragma unroll
  for (int it = 0; it < 24; it++) {
    int idx = tid + it * 256;  // 0..6143
    int kr = idx / 192, n = idx % 192;
    T[n][kr] = (short)f2bf(Wp[(size_t)kr * 192 + n]);
  }
  __syncthreads();
  unsigned short* Wo = Wt + (size_t)e * 192 * 1024 + k0;
#pragma unroll
  for (int it = 0; it < 3; it++) {
    int idx = tid + it * 256;  // 0..767
    int n = idx >> 2, c = idx & 3;
    bf16x8 v = *reinterpret_cast<bf16x8*>(&T[n][c * 8]);
    *reinterpret_cast<bf16x8*>(Wo + (size_t)n * 1024 + c * 8) = v;
  }
}

// W_ff[e][64 k][1024 n] f32 -> Wt[e][1024 n][64 k] bf16
__global__ __launch_bounds__(256) void cvt_wff_kernel(
    const float* __restrict__ W, unsigned short* __restrict__ Wt) {
  __shared__ short T[64][72];
  int e = blockIdx.y, n0 = blockIdx.x * 64;
  const float* Wp = W + (size_t)e * DH_ * D_;
  int tid = threadIdx.x;
#pragma unroll
  for (int it = 0; it < 16; it++) {
    int idx = tid + it * 256;  // 0..4095
    int k = idx >> 6, n = idx & 63;
    T[n][k] = (short)f2bf(Wp[(size_t)k * D_ + n0 + n]);
  }
  __syncthreads();
  unsigned short* Wo = Wt + (size_t)e * D_ * DH_ + (size_t)n0 * DH_;
#pragma unroll
  for (int it = 0; it < 2; it++) {
    int idx = tid + it * 256;  // 0..511
    int n = idx >> 3, c = idx & 7;
    bf16x8 v = *reinterpret_cast<bf16x8*>(&T[n][c * 8]);
    *reinterpret_cast<bf16x8*>(Wo + (size_t)n * DH_ + c * 8) = v;
  }
}

// ---------------- Kernel 1: gating -> masked_t[e][b][s] ----------------
__global__ __launch_bounds__(256) void gate_kernel(
    const float* __restrict__ X, const float* __restrict__ wg,
    const float* __restrict__ bg, float* __restrict__ masked_t) {
  int token = blockIdx.x * 4 + (threadIdx.x >> 6);  // b*S + s
  int lane = threadIdx.x & 63;
  int b = token / S_, s = token % S_;
  const float* xrow = X + (size_t)token * D_;
  float acc[E_];
#pragma unroll
  for (int e = 0; e < E_; e++) acc[e] = 0.f;
  for (int d = lane; d < D_; d += 64) {
    float xv = xrow[d];
    const float* wrow = wg + (size_t)d * E_;
#pragma unroll
    for (int e = 0; e < E_; e++) acc[e] += xv * wrow[e];
  }
#pragma unroll
  for (int e = 0; e < E_; e++) {
    float v = acc[e];
    for (int off = 32; off; off >>= 1) v += __shfl_xor(v, off);
    acc[e] = v;
  }
  if (lane == 0) {
    float lg[E_], sc[E_], mx = -1e30f;
#pragma unroll
    for (int e = 0; e < E_; e++) {
      lg[e] = acc[e] + bg[e];
      mx = fmaxf(mx, lg[e]);
    }
    float den = 0.f;
#pragma unroll
    for (int e = 0; e < E_; e++) {
      sc[e] = expf(lg[e] - mx);
      den += sc[e];
    }
#pragma unroll
    for (int e = 0; e < E_; e++) sc[e] /= den;
#pragma unroll
    for (int e = 0; e < E_; e++) {
      int rank = 0;
      for (int j = 0; j < E_; j++)
        if (lg[j] > lg[e] || (lg[j] == lg[e] && j < e)) rank++;
      float m = (rank < TOPK_) ? sc[e] : 0.f;
      masked_t[((size_t)e * B_ + b) * S_ + s] = m;
    }
  }
}

// ---------------- Kernel 2: route_t = masked/denom*CAP ----------------
__global__ __launch_bounds__(256) void route_kernel(
    const float* __restrict__ masked_t, float* __restrict__ route_t) {
  int i = blockIdx.x * blockDim.x + threadIdx.x;  // over E*S
  if (i >= E_ * S_) return;
  int e = i / S_, s = i % S_;
  float v[B_];
  float d = EPS_;
#pragma unroll
  for (int b = 0; b < B_; b++) {
    v[b] = masked_t[((size_t)e * B_ + b) * S_ + s];
    d += v[b];
  }
#pragma unroll
  for (int b = 0; b < B_; b++)
    route_t[((size_t)e * B_ + b) * S_ + s] = v[b] / d * CAPF;
}

// ---------------- Kernel 3: top-MAXLEN selection per (e,b) ----------------
__global__ __launch_bounds__(1024) void select_kernel(
    const float* __restrict__ route_t, int* __restrict__ seq_ids) {
  __shared__ unsigned long long keys[S_];
  __shared__ int flags[S_];
  __shared__ int sA[S_], sB[S_];
  int eb = blockIdx.x;
  const float* r = route_t + (size_t)eb * S_;
  int tid = threadIdx.x;
  for (int i = tid; i < S_; i += 1024) {
    unsigned int fb = __float_as_uint(r[i]);  // monotonic, r >= 0
    keys[i] = ((unsigned long long)fb << 32) | (unsigned int)(S_ - 1 - i);
  }
  __syncthreads();
  for (int k = 2; k <= S_; k <<= 1) {
    for (int j = k >> 1; j > 0; j >>= 1) {
      for (int i = tid; i < S_; i += 1024) {
        int ixj = i ^ j;
        if (ixj > i) {
          bool desc = ((i & k) == 0);
          unsigned long long a = keys[i], c = keys[ixj];
          bool sw = desc ? (a < c) : (a > c);
          if (sw) { keys[i] = c; keys[ixj] = a; }
        }
      }
      __syncthreads();
    }
  }
  for (int i = tid; i < S_; i += 1024) flags[i] = 0;
  __syncthreads();
  for (int i = tid; i < MAXLEN_; i += 1024) {
    int s = S_ - 1 - (int)(keys[i] & 0xFFFFFFFFull);
    flags[s] = 1;
  }
  __syncthreads();
  for (int i = tid; i < S_; i += 1024) sA[i] = flags[i];
  __syncthreads();
  int* src = sA;
  int* dst = sB;
  for (int off = 1; off < S_; off <<= 1) {
    for (int i = tid; i < S_; i += 1024)
      dst[i] = src[i] + ((i >= off) ? src[i - off] : 0);
    __syncthreads();
    int* t = src; src = dst; dst = t;
  }
  int* outp = seq_ids + (size_t)eb * MAXLEN_;
  for (int i = tid; i < S_; i += 1024)
    if (flags[i]) outp[src[i] - 1] = i;
}

// ---------------- Kernel 4: gathered QKV GEMM (bf16 MFMA) ----------------
// qkv[eb][m][0:192] = Xb16[b][sid[m]][:] @ Wt_qkv[e]^T
// BM=128 (8 waves), BK=64. A-frags direct from global; B staged in LDS.
__global__ __launch_bounds__(512) void qkv_kernel(
    const unsigned short* __restrict__ Xb, const unsigned short* __restrict__ Wt,
    const int* __restrict__ seq_ids, unsigned short* __restrict__ qkv) {
  __shared__ __align__(16) char Bt_[192 * 128];  // [192 n][64 k] bf16 swz128
  __shared__ int rows[128];
  int eb = blockIdx.y;
  int e = eb >> 2, b = eb & 3;
  int m0 = blockIdx.x * 128;
  int tid = threadIdx.x;
  int w = tid >> 6, l = tid & 63, lr = l & 15, lg = l >> 4;
  const int* sid = seq_ids + (size_t)eb * MAXLEN_;
  if (tid < 128) {
    int m = m0 + tid;
    rows[tid] = (m < MAXLEN_) ? sid[m] : 0;
  }
  __syncthreads();
  const unsigned short* Wm = Wt + (size_t)e * 192 * 1024;
  const unsigned short* aptr = Xb + (size_t)b * S_ * D_ + (size_t)rows[w * 16 + lr] * D_;
  f32x4 acc[12];
#pragma unroll
  for (int nb = 0; nb < 12; nb++) acc[nb] = (f32x4){0.f, 0.f, 0.f, 0.f};
  for (int k0 = 0; k0 < D_; k0 += 64) {
#pragma unroll
    for (int it = 0; it < 3; it++) {
      int idx = tid + it * 512;  // 0..1535
      int row = idx >> 3, c = idx & 7;
      bf16x8 v = *reinterpret_cast<const bf16x8*>(Wm + (size_t)row * 1024 + k0 + c * 8);
      *reinterpret_cast<bf16x8*>(Bt_ + swz128(row, c * 16)) = v;
    }
    __syncthreads();
#pragma unroll
    for (int ks = 0; ks < 2; ks++) {
      bf16x8 af = *reinterpret_cast<const bf16x8*>(aptr + k0 + ks * 32 + lg * 8);
#pragma unroll
      for (int nb = 0; nb < 12; nb++) {
        bf16x8 bfr = *reinterpret_cast<bf16x8*>(Bt_ + swz128(nb * 16 + lr, ks * 64 + lg * 16));
        acc[nb] = mfma16(af, bfr, acc[nb]);
      }
    }
    __syncthreads();
  }
  unsigned short* outp = qkv + (size_t)eb * MAXLEN_ * 192;
#pragma unroll
  for (int nb = 0; nb < 12; nb++) {
#pragma unroll
    for (int i = 0; i < 4; i++) {
      int m = m0 + w * 16 + lg * 4 + i;
      if (m < MAXLEN_) outp[(size_t)m * 192 + nb * 16 + lr] = f2bf(acc[nb][i]);
    }
  }
}

// ------------- Kernel 5: flash attention, bf16 MFMA, per (e,b) -------------
__global__ __launch_bounds__(256) void attn_kernel(
    const unsigned short* __restrict__ qkv, unsigned short* __restrict__ ctx) {
  __shared__ __align__(16) char Ks_[64 * 128];   // [64 k][64 d] bf16 swz128
  __shared__ __align__(16) char Vt_[64 * 128];   // [64 dv][64 k] bf16 swz128
  __shared__ __align__(16) char Pl_[4 * 16 * 128];  // per-wave [16 q][64 k]
  int qt = (NQT_ - 1) - blockIdx.x;  // longest blocks first
  int eb = blockIdx.y;
  const unsigned short* base = qkv + (size_t)eb * MAXLEN_ * 192;
  int tid = threadIdx.x;
  int w = tid >> 6, l = tid & 63, lr = l & 15, lg = l >> 4;
  int q0 = qt * 64;
  int gq = q0 + w * 16 + lr;  // this lane's q column
  bf16x8 qf[2];
  {
    int m = (gq < MAXLEN_) ? gq : 0;
    const unsigned short* qp = base + (size_t)m * 192;
#pragma unroll
    for (int ds = 0; ds < 2; ds++) {
      int d0 = ds * 32 + lg * 8;
#pragma unroll
      for (int j = 0; j < 8; j++)
        qf[ds][j] = (short)f2bf(bf2f(qp[d0 + j]) * 0.125f);
    }
  }
  f32x4 acc[4];
#pragma unroll
  for (int db = 0; db < 4; db++) acc[db] = (f32x4){0.f, 0.f, 0.f, 0.f};
  float mrow = -1e30f, lsum = 0.f;
  char* Pw = Pl_ + w * 2048;
  for (int kt = 0; kt <= qt; kt++) {
    int k0 = kt * 64;
#pragma unroll
    for (int it = 0; it < 4; it++) {
      int idx = tid + it * 256;  // 0..1023
      int row = idx >> 4, cq = (idx & 15) * 4;
      int m = k0 + row;
      ushort4 kv, vv;
      if (m < MAXLEN_) {
        kv = *reinterpret_cast<const ushort4*>(base + (size_t)m * 192 + 64 + cq);
        vv = *reinterpret_cast<const ushort4*>(base + (size_t)m * 192 + 128 + cq);
      } else {
        kv.x = kv.y = kv.z = kv.w = 0;
        vv.x = vv.y = vv.z = vv.w = 0;
      }
      *reinterpret_cast<ushort4*>(Ks_ + swz128(row, cq * 2)) = kv;
      *reinterpret_cast<unsigned short*>(Vt_ + swz128(cq + 0, row * 2)) = vv.x;
      *reinterpret_cast<unsigned short*>(Vt_ + swz128(cq + 1, row * 2)) = vv.y;
      *reinterpret_cast<unsigned short*>(Vt_ + swz128(cq + 2, row * 2)) = vv.z;
      *reinterpret_cast<unsigned short*>(Vt_ + swz128(cq + 3, row * 2)) = vv.w;
    }
    __syncthreads();
    f32x4 sac[4];
#pragma unroll
    for (int kb = 0; kb < 4; kb++) {
      sac[kb] = (f32x4){0.f, 0.f, 0.f, 0.f};
#pragma unroll
      for (int ds = 0; ds < 2; ds++) {
        bf16x8 kf = *reinterpret_cast<bf16x8*>(Ks_ + swz128(kb * 16 + lr, ds * 64 + lg * 16));
        sac[kb] = mfma16(kf, qf[ds], sac[kb]);
      }
    }
    float p[16];
    float tmax = -1e30f;
#pragma unroll
    for (int kb = 0; kb < 4; kb++) {
#pragma unroll
      for (int i = 0; i < 4; i++) {
        int k = k0 + kb * 16 + lg * 4 + i;
        float s = sac[kb][i];
        if (k > gq || k >= MAXLEN_) s = -1e9f;
        p[kb * 4 + i] = s;
        tmax = fmaxf(tmax, s);
      }
    }
    tmax = fmaxf(tmax, __shfl_xor(tmax, 16));
    tmax = fmaxf(tmax, __shfl_xor(tmax, 32));
    float mnew = fmaxf(mrow, tmax);
    float corr = __expf(mrow - mnew);
    float psum = 0.f;
#pragma unroll
    for (int j = 0; j < 16; j++) {
      p[j] = __expf(p[j] - mnew);
      psum += p[j];
    }
    psum += __shfl_xor(psum, 16);
    psum += __shfl_xor(psum, 32);
    lsum = lsum * corr + psum;
    mrow = mnew;
#pragma unroll
    for (int db = 0; db < 4; db++) acc[db] = acc[db] * corr;
#pragma unroll
    for (int kb = 0; kb < 4; kb++) {
#pragma unroll
      for (int ip = 0; ip < 2; ip++) {
        unsigned u = (unsigned)f2bf(p[kb * 4 + ip * 2]) |
                     ((unsigned)f2bf(p[kb * 4 + ip * 2 + 1]) << 16);
        int k = kb * 16 + lg * 4 + ip * 2;
        *reinterpret_cast<unsigned*>(Pw + swz128(lr, k * 2)) = u;
      }
    }
    bf16x8 pf[2];
#pragma unroll
    for (int ks = 0; ks < 2; ks++)
      pf[ks] = *reinterpret_cast<bf16x8*>(Pw + swz128(lr, ks * 64 + lg * 16));
#pragma unroll
    for (int db = 0; db < 4; db++) {
#pragma unroll
      for (int ks = 0; ks < 2; ks++) {
        bf16x8 vf = *reinterpret_cast<bf16x8*>(Vt_ + swz128(db * 16 + lr, ks * 64 + lg * 16));
        acc[db] = mfma16(vf, pf[ks], acc[db]);
      }
    }
    __syncthreads();
  }
  if (gq < MAXLEN_) {
    float inv = 1.f / lsum;
    unsigned short* op = ctx + ((size_t)eb * MAXLEN_ + gq) * DH_;
#pragma unroll
    for (int db = 0; db < 4; db++) {
#pragma unroll
      for (int ip = 0; ip < 2; ip++) {
        unsigned u = (unsigned)f2bf(acc[db][ip * 2] * inv) |
                     ((unsigned)f2bf(acc[db][ip * 2 + 1] * inv) << 16);
        *reinterpret_cast<unsigned*>(op + db * 16 + lg * 4 + ip * 2) = u;
      }
    }
  }
}

// ------- Kernel 6: FF GEMM (bf16 MFMA) -> outb[e][m][:] for batch b -------
__global__ __launch_bounds__(256) void ff_kernel(
    const unsigned short* __restrict__ ctx, const unsigned short* __restrict__ Wtff,
    const float* __restrict__ bff, unsigned short* __restrict__ outb, int b) {
  __shared__ __align__(16) char As_[128 * 128];  // [128 m][64 k] bf16 swz128
  __shared__ __align__(16) char Bt_[128 * 128];  // [128 n][64 k] bf16 swz128
  int e = blockIdx.z;
  int m0 = blockIdx.y * 128, n0 = blockIdx.x * 128;
  int tid = threadIdx.x;
  int w = tid >> 6, l = tid & 63, lr = l & 15, lg = l >> 4;
  const unsigned short* A = ctx + (size_t)(e * B_ + b) * MAXLEN_ * DH_;
  const unsigned short* Wm = Wtff + (size_t)e * D_ * DH_;
#pragma unroll
  for (int it = 0; it < 8; it++) {
    int idx = tid + it * 256;  // 0..2047
    int row = idx >> 4, kq = (idx & 15) * 4;
    int gm = m0 + row;
    if (gm >= MAXLEN_) gm = MAXLEN_ - 1;
    ushort4 av = *reinterpret_cast<const ushort4*>(A + (size_t)gm * DH_ + kq);
    *reinterpret_cast<ushort4*>(As_ + swz128(row, kq * 2)) = av;
  }
#pragma unroll
  for (int it = 0; it < 4; it++) {
    int idx = tid + it * 256;  // 0..1023
    int row = idx >> 3, c = idx & 7;
    bf16x8 v = *reinterpret_cast<const bf16x8*>(Wm + (size_t)(n0 + row) * DH_ + c * 8);
    *reinterpret_cast<bf16x8*>(Bt_ + swz128(row, c * 16)) = v;
  }
  __syncthreads();
  int wm = w >> 1, wn = w & 1;
  f32x4 acc[4][4];
#pragma unroll
  for (int mb = 0; mb < 4; mb++)
#pragma unroll
    for (int nb = 0; nb < 4; nb++) acc[mb][nb] = (f32x4){0.f, 0.f, 0.f, 0.f};
#pragma unroll
  for (int ks = 0; ks < 2; ks++) {
    bf16x8 af[4], bfr[4];
#pragma unroll
    for (int mb = 0; mb < 4; mb++)
      af[mb] = *reinterpret_cast<bf16x8*>(As_ + swz128(wm * 64 + mb * 16 + lr, ks * 64 + lg * 16));
#pragma unroll
    for (int nb = 0; nb < 4; nb++)
      bfr[nb] = *reinterpret_cast<bf16x8*>(Bt_ + swz128(wn * 64 + nb * 16 + lr, ks * 64 + lg * 16));
#pragma unroll
    for (int mb = 0; mb < 4; mb++)
#pragma unroll
      for (int nb = 0; nb < 4; nb++)
        acc[mb][nb] = mfma16(af[mb], bfr[nb], acc[mb][nb]);
  }
  float bias[4];
#pragma unroll
  for (int nb = 0; nb < 4; nb++)
    bias[nb] = bff[(size_t)e * D_ + n0 + wn * 64 + nb * 16 + lr];
#pragma unroll
  for (int mb = 0; mb < 4; mb++) {
#pragma unroll
    for (int i = 0; i < 4; i++) {
      int m = m0 + wm * 64 + mb * 16 + lg * 4 + i;
      if (m < MAXLEN_) {
        unsigned short* orow = outb + ((size_t)e * MAXLEN_ + m) * D_ + n0 + wn * 64;
#pragma unroll
        for (int nb = 0; nb < 4; nb++)
          orow[nb * 16 + lr] = f2bf(acc[mb][nb][i] + bias[nb]);
      }
    }
  }
}

// ------- Kernel 7: per-token gather (binary search) + residual + LayerNorm -
__global__ __launch_bounds__(256) void gather_ln_kernel(
    const float* __restrict__ X, const unsigned short* __restrict__ outb,
    const int* __restrict__ seq_ids, const float* __restrict__ gamma,
    const float* __restrict__ beta, float* __restrict__ out, int b) {
  __shared__ int ms[E_];
  __shared__ float w1[4], w2[4];
  int s = blockIdx.x;
  int tid = threadIdx.x;
  if (tid < E_) {
    const int* sid = seq_ids + ((size_t)tid * B_ + b) * MAXLEN_;
    int lo = 0, hi = MAXLEN_;
    while (lo < hi) {
      int mid = (lo + hi) >> 1;
      if (sid[mid] < s) lo = mid + 1; else hi = mid;
    }
    ms[tid] = (lo < MAXLEN_ && sid[lo] == s) ? lo : -1;
  }
  __syncthreads();
  const float* xr = X + ((size_t)b * S_ + s) * D_;
  float4 xv = *reinterpret_cast<const float4*>(xr + tid * 4);
  float v[4] = {xv.x, xv.y, xv.z, xv.w};
#pragma unroll
  for (int e = 0; e < E_; e++) {
    int m = ms[e];
    if (m >= 0) {
      const unsigned short* orow = outb + ((size_t)e * MAXLEN_ + m) * D_;
      ushort4 u = *reinterpret_cast<const ushort4*>(orow + tid * 4);
      v[0] += bf2f(u.x); v[1] += bf2f(u.y); v[2] += bf2f(u.z); v[3] += bf2f(u.w);
    }
  }
  float s1 = v[0] + v[1] + v[2] + v[3];
  float s2 = v[0] * v[0] + v[1] * v[1] + v[2] * v[2] + v[3] * v[3];
  for (int off = 32; off; off >>= 1) {
    s1 += __shfl_xor(s1, off);
    s2 += __shfl_xor(s2, off);
  }
  int wv = tid >> 6;
  if ((tid & 63) == 0) { w1[wv] = s1; w2[wv] = s2; }
  __syncthreads();
  s1 = w1[0] + w1[1] + w1[2] + w1[3];
  s2 = w2[0] + w2[1] + w2[2] + w2[3];
  float mu = s1 * (1.f / D_);
  float var = s2 * (1.f / D_) - mu * mu;
  float inv = rsqrtf(var + 1e-5f);
  float4 g = *reinterpret_cast<const float4*>(gamma + tid * 4);
  float4 be = *reinterpret_cast<const float4*>(beta + tid * 4);
  float4 o;
  o.x = (v[0] - mu) * inv * g.x + be.x;
  o.y = (v[1] - mu) * inv * g.y + be.y;
  o.z = (v[2] - mu) * inv * g.z + be.z;
  o.w = (v[3] - mu) * inv * g.w + be.w;
  *reinterpret_cast<float4*>(out + ((size_t)b * S_ + s) * D_ + tid * 4) = o;
}

extern "C" void kernel_launch(void* const* d_in, const int* in_sizes, int n_in,
                              void* d_out, int out_size, void* d_ws, size_t ws_size,
                              hipStream_t stream) {
  const float* X = (const float*)d_in[0];
  // d_in[1] = attn_mask (causal, hardcoded)
  const float* w_gate = (const float*)d_in[2];
  const float* b_gate = (const float*)d_in[3];
  const float* W_qkv = (const float*)d_in[4];
  const float* W_ff = (const float*)d_in[5];
  const float* b_ff = (const float*)d_in[6];
  const float* ln_g = (const float*)d_in[7];
  const float* ln_b = (const float*)d_in[8];
  float* out = (float*)d_out;

  char* ws = (char*)d_ws;
  float* masked_t = (float*)(ws);                           //   524288 B
  float* route_t = (float*)(ws + 524288);                   //   524288 B
  int* seq_ids = (int*)(ws + 1048576);                      //   314368 B
  unsigned short* qkv = (unsigned short*)(ws + 1362944);    // 30179328 B
  unsigned short* ctx = (unsigned short*)(ws + 31542272);   // 10059776 B
  unsigned short* outb = (unsigned short*)(ws + 41602048);  // 40239104 B
  unsigned short* Xb16 = (unsigned short*)(ws + 81841152);  // 16777216 B
  unsigned short* Wtq = (unsigned short*)(ws + 98618368);   //  6291456 B
  unsigned short* Wtf = (unsigned short*)(ws + 104909824);  //  2097152 B
  // total 107006976 B

  cvt_x_kernel<<<4096, 256, 0, stream>>>(X, Xb16);
  cvt_wqkv_kernel<<<dim3(32, 16), 256, 0, stream>>>(W_qkv, Wtq);
  cvt_wff_kernel<<<dim3(16, 16), 256, 0, stream>>>(W_ff, Wtf);
  gate_kernel<<<2048, 256, 0, stream>>>(X, w_gate, b_gate, masked_t);
  route_kernel<<<(E_ * S_ + 255) / 256, 256, 0, stream>>>(masked_t, route_t);
  select_kernel<<<E_ * B_, 1024, 0, stream>>>(route_t, seq_ids);
  qkv_kernel<<<dim3(10, 64), 512, 0, stream>>>(Xb16, Wtq, seq_ids, qkv);
  attn_kernel<<<dim3(NQT_, 64), 256, 0, stream>>>(qkv, ctx);
  for (int b = 0; b < B_; b++) {
    ff_kernel<<<dim3(8, 10, 16), 256, 0, stream>>>(ctx, Wtf, b_ff, outb, b);
    gather_ln_kernel<<<S_, 256, 0, stream>>>(X, outb, seq_ids, ln_g, ln_b, out, b);
  }
}